// Round 12
// baseline (131.161 us; speedup 1.0000x reference)
//
#include <hip/hip_runtime.h>

// LPC synthesis (AR(15), frame-hopped coefs) + de-emphasis IIR.
//
// R18: WARM-UP FROM GLOBAL, STAGE ONLY THE EMIT REGION (barrier decouple).
// R17 measured 41 us with ideal traffic (FETCH 39.7 MB, WRITE 60 MB) and
// VALUBusy 41% -> phase-serialization fits: stage 6.3 + compute ~17 +
// store 9.5 + ~8 slop. This round removes the serial coupling around the
// staging barrier:
//  - warm-up (48 samples) reads straight from GLOBAL. Its lines were just
//    requested by the coalesced staging loads -> L1/L2 hits / in-flight
//    merges, NOT R16's exposed HBM misses (R16 lacked the coalesced
//    primer; its scattered reads went to HBM: FETCH 56 MB, 51.5 us).
//  - warm-up therefore needs NO LDS -> the stage->warm barrier vanishes;
//    the one barrier before emit covers staging visibility AND the
//    staging drain hides under ~1700 cyc of warm-up math.
//  - staged region = exactly 128 slots (emit slot = tid): staging is
//    exactly 10 lane-consecutive float4s per thread (full 1 KB bursts per
//    wave, no tail). LDS 128 x 176 B + 1 KB = 23.5 KB -> 6 blocks/CU.
// Numerics identical to R17 (absmax 0.0078125): 48-sample AR warm-up
// (rho^48), fp32 staging + fp32 in-place z writeback, 9-term Neumann
// de-emph init (r = 0.97^40, residual ~4e-4), pre-signal masking,
// odd/even tap select, fmaf(-a,..) neg-modifier folding.
// Phase chain (3 barriers): [stage issue + tap loads + warm(global)]
// bar [emit -> z in own slot, zend] bar [zp] bar [coalesced store].
// Kept lessons: R8 scattered stores write-amplify 2.6x -> LDS-coalesced
// store; R13 no big live register arrays; R15 no multi-tile store drain.

namespace {
constexpr int kHS = 40;         // samples per half-frame
constexpr int kF = 3000;        // frames per batch
constexpr int kH = 2 * kF;      // 6000 half-frames per batch
constexpr int kL = kHS * kH;    // 240000
constexpr int kL4 = kL / 4;     // 60000 float4s per batch row
constexpr int kOrder = 16;
constexpr int kB = 64;
constexpr float kEmph = 0.97f;
constexpr int kThreads = 128;   // 2 waves/block
constexpr int kJunk = 9;        // 9-term correction needs 9 lead lanes
constexpr int kEmitH = kThreads - kJunk;  // 119 half-frames per block
constexpr int kSlotW = 44;      // words per LDS slot (176 B, 16B-aligned)
constexpr int kCols = 51;       // ceil(6000/119)
constexpr float kLg97 = -4.3943347e-2f;  // log2(0.97)
// powers of r = 0.97^40
constexpr float kR1 = 0.2957118f;
constexpr float kR2 = 0.08744547f;
constexpr float kR3 = 0.02585867f;
constexpr float kR4 = 0.00764671f;
constexpr float kR5 = 0.00226126f;
constexpr float kR6 = 6.6867e-4f;
constexpr float kR7 = 1.9773e-4f;
constexpr float kR8 = 5.8472e-5f;

typedef float vfloat4 __attribute__((ext_vector_type(4)));
}  // namespace

// One AR sample; 3 partial accumulators keep the cross-sample critical
// path at 1 fma + 1 add (8 cyc) vs ~38 cyc of issue. Taps consumed as
// -A[k] via the fmaf neg source modifier (zero cost).
#define AR_SAMPLE(A, s, e_in, ACC)                                         \
  float ACC;                                                               \
  {                                                                        \
    float t0 = (e_in);                                                     \
    t0 = fmaf(-A[14], x[((s)-15) & 15], t0);                               \
    t0 = fmaf(-A[13], x[((s)-14) & 15], t0);                               \
    t0 = fmaf(-A[12], x[((s)-13) & 15], t0);                               \
    t0 = fmaf(-A[11], x[((s)-12) & 15], t0);                               \
    t0 = fmaf(-A[10], x[((s)-11) & 15], t0);                               \
    float t1 = -A[9] * x[((s)-10) & 15];                                   \
    t1 = fmaf(-A[8], x[((s)-9) & 15], t1);                                 \
    t1 = fmaf(-A[7], x[((s)-8) & 15], t1);                                 \
    t1 = fmaf(-A[6], x[((s)-7) & 15], t1);                                 \
    t1 = fmaf(-A[5], x[((s)-6) & 15], t1);                                 \
    float t2 = -A[4] * x[((s)-5) & 15];                                    \
    t2 = fmaf(-A[3], x[((s)-4) & 15], t2);                                 \
    t2 = fmaf(-A[2], x[((s)-3) & 15], t2);                                 \
    t2 = fmaf(-A[1], x[((s)-2) & 15], t2);                                 \
    const float t01 = t0 + t1;               /* off critical path */       \
    t2 = fmaf(-A[0], x[((s)-1) & 15], t2);   /* critical: 1 fma */         \
    ACC = t01 + t2;                          /* + 1 add */                 \
    x[(s)&15] = ACC;                                                       \
  }

__global__ __launch_bounds__(kThreads) void lpc_synth_kernel(
    const float* __restrict__ excit, const float* __restrict__ coef,
    float* __restrict__ out) {
  __shared__ float s_x[kThreads * kSlotW];  // 22528 B: emit input, then z
  __shared__ float s_zend[kThreads];        //   512 B: per-lane zh
  __shared__ float s_zp[kThreads];          //   512 B: per-output Zp

  const int tid = threadIdx.x;
  const int b = blockIdx.y;
  const int hbase = blockIdx.x * kEmitH;
  const int ht = hbase + tid - kJunk;  // half-frame this lane emits
  const int hc = min(max(ht, 0), kH - 1);
  const int h1 = min(max(ht - 1, 0), kH - 1);
  const int h2 = min(max(ht - 2, 0), kH - 1);

  const float* __restrict__ ebase = excit + (size_t)b * kL;
  const float* __restrict__ cbase = coef + (size_t)b * kF * kOrder;

  // ---- Coalesced staging of the emit region: slot s <-> half-frame
  // hbase - 9 + s (lane's emit slot = tid). Exactly 1280 float4s =
  // 10 per thread, lane-consecutive -> full 1 KB bursts per wave.
  {
    const vfloat4* __restrict__ eg = (const vfloat4*)ebase;
    const int base4 = (hbase - kJunk) * 10;  // float4 index of slot0
#pragma unroll
    for (int p = 0; p < 10; ++p) {
      const int i = tid + p * kThreads;
      const int g4 = min(max(base4 + i, 0), kL4 - 1);
      const vfloat4 v = eg[g4];
      const int slot = i / 10;
      const int o = i - slot * 10;
      *(vfloat4*)(s_x + slot * kSlotW + o * 4) = v;
    }
  }

  // ---- Tap loads (prev frame for warm-up, cur frame for emit): 64 B
  // lane stride, cache-absorbed (R12-measured).
  const vfloat4* __restrict__ cp_ =
      (const vfloat4*)(cbase + (size_t)(h2 >> 1) * kOrder);
  const vfloat4* __restrict__ cc_ =
      (const vfloat4*)(cbase + (size_t)(hc >> 1) * kOrder);
  const vfloat4 p0 = cp_[0], p1 = cp_[1], p2 = cp_[2], p3 = cp_[3];
  const vfloat4 q0 = cc_[0], q1 = cc_[1], q2 = cc_[2], q3 = cc_[3];

  float pa_[15] = {p0.y, p0.z, p0.w, p1.x, p1.y, p1.z, p1.w, p2.x,
                   p2.y, p2.z, p2.w, p3.x, p3.y, p3.z, p3.w};
  const float ca_[15] = {q0.y, q0.z, q0.w, q1.x, q1.y, q1.z, q1.w, q2.x,
                         q2.y, q2.z, q2.w, q3.x, q3.y, q3.z, q3.w};

  // Ring buffer of last 16 y-samples; local sample counter s = 0..87
  // (warm 0..47, emit 48..87). Compile-time indexed -> VGPRs.
  float x[16];
#pragma unroll
  for (int i = 0; i < 16; ++i) x[i] = 0.f;

  // ---- Warm-up 48 samples from GLOBAL (no LDS dependency -> runs while
  // the staging drain completes; lines are L1/L2-hot from the staging
  // burst above). Pre-signal inputs masked to zero.
  {
    const vfloat4* __restrict__ e2 = (const vfloat4*)(ebase + h2 * kHS);
    const vfloat4* __restrict__ e1 = (const vfloat4*)(ebase + h1 * kHS);
    const float m2 = (ht >= 2) ? 1.f : 0.f;
    const float m1 = (ht >= 1) ? 1.f : 0.f;
    // Samples 0..7: tail (words 32..39) of half-frame ht-2, prev taps.
#pragma unroll
    for (int j = 8; j < 10; ++j) {
      const vfloat4 v = e2[j];
      const float f_[4] = {m2 * v.x, m2 * v.y, m2 * v.z, m2 * v.w};
#pragma unroll
      for (int q = 0; q < 4; ++q) {
        AR_SAMPLE(pa_, 4 * (j - 8) + q, f_[q], acc)
        (void)acc;
      }
    }
    // Half-frame ht-1 belongs to the emit frame when ht is odd: one-time
    // tap select (masked lanes don't care).
    if (ht & 1) {
#pragma unroll
      for (int k = 0; k < 15; ++k) pa_[k] = ca_[k];
    }
    // Samples 8..47: half-frame ht-1 in full.
#pragma unroll
    for (int j = 0; j < 10; ++j) {
      const vfloat4 v = e1[j];
      const float f_[4] = {m1 * v.x, m1 * v.y, m1 * v.z, m1 * v.w};
#pragma unroll
      for (int q = 0; q < 4; ++q) {
        AR_SAMPLE(pa_, 8 + 4 * j + q, f_[q], acc)
        (void)acc;
      }
    }
  }
  // Single pre-emit fence: all staging writes visible (emit reads its own
  // slot, written cooperatively by other lanes). Warm-up read no LDS, so
  // no other hazard exists.
  __syncthreads();

  // ---- Emit 40 samples: input from own slot (tid), z (fp32) written
  // back IN PLACE (read v before write; no cross-lane access).
  float z = 0.f;
  {
    float* __restrict__ so = s_x + tid * kSlotW;
#pragma unroll
    for (int j = 0; j < 10; ++j) {
      const vfloat4 v = *(const vfloat4*)(so + 4 * j);
      vfloat4 zv;
#pragma unroll
      for (int q = 0; q < 4; ++q) {
        AR_SAMPLE(ca_, 48 + 4 * j + q, v[q], acc)
        z = fmaf(kEmph, z, acc);  // de-emph over this half-frame only
        if (q == 0) zv.x = z;
        if (q == 1) zv.y = z;
        if (q == 2) zv.z = z;
        if (q == 3) zv.w = z;
      }
      *(vfloat4*)(so + 4 * j) = zv;
    }
  }
  // zh = 0 outside the signal so correction terms vanish automatically.
  s_zend[tid] = (ht < 0 || ht >= kH) ? 0.f : z;
  __syncthreads();

  // ---- Per-output de-emph init (9-term Neumann, r = 0.97^40):
  // output k (block-local): Zp = sum_{i=1..9} r^(i-1) * zh[hbase+k-i],
  // i.e. s_zend[k+8] .. s_zend[k].
  if (tid < kEmitH) {
    float Zp = s_zend[tid + 8];
    Zp = fmaf(kR1, s_zend[tid + 7], Zp);
    Zp = fmaf(kR2, s_zend[tid + 6], Zp);
    Zp = fmaf(kR3, s_zend[tid + 5], Zp);
    Zp = fmaf(kR4, s_zend[tid + 4], Zp);
    Zp = fmaf(kR5, s_zend[tid + 3], Zp);
    Zp = fmaf(kR6, s_zend[tid + 2], Zp);
    Zp = fmaf(kR7, s_zend[tid + 1], Zp);
    Zp = fmaf(kR8, s_zend[tid + 0], Zp);
    s_zp[tid] = Zp;
  }
  __syncthreads();

  // ---- Coalesced store + correction: z_exact(s) = z_loc(s)+0.97^(s+1)*Zp.
  // Output k lives in slot k+9 (lane k+9's emit slot). Lane-consecutive
  // float4s: full 1 KB bursts per wave (R8/R9 lesson).
  {
    const int nv4 = min(kEmitH, kH - hbase) * 10;
    vfloat4* __restrict__ ob =
        (vfloat4*)(out + (size_t)b * kL + (size_t)hbase * kHS);
#pragma unroll 1
    for (int i = tid; i < nv4; i += kThreads) {
      const int k = i / 10;  // half-frame within block
      const int j = i - 10 * k;
      const vfloat4 h =
          *(const vfloat4*)(s_x + (k + kJunk) * kSlotW + 4 * j);
      const float Zp = s_zp[k];
      const float ee = __builtin_exp2f(kLg97 * (float)(4 * j + 1));
      vfloat4 v;
      v.x = fmaf(ee, Zp, h.x);
      v.y = fmaf(ee * 0.97f, Zp, h.y);
      v.z = fmaf(ee * 0.9409f, Zp, h.z);
      v.w = fmaf(ee * 0.912673f, Zp, h.w);
      ob[i] = v;
    }
  }
}
#undef AR_SAMPLE

extern "C" void kernel_launch(void* const* d_in, const int* in_sizes, int n_in,
                              void* d_out, int out_size, void* d_ws,
                              size_t ws_size, hipStream_t stream) {
  const float* excit = (const float*)d_in[0];  // (B, L, 1) fp32
  const float* coef = (const float*)d_in[1];   // (B, F, 16) fp32
  float* out = (float*)d_out;                  // (B, L, 1) fp32

  dim3 grid(kCols, kB);  // 51 x 64 blocks of 128
  lpc_synth_kernel<<<grid, kThreads, 0, stream>>>(excit, coef, out);
}

// Round 13
// 126.266 us; speedup vs baseline: 1.0388x; 1.0388x over previous
//
#include <hip/hip_runtime.h>

// LPC synthesis (AR(15), frame-hopped coefs) + de-emphasis IIR.
//
// R19: SINGLE-WAVE BLOCKS (R17 numerics, 64-lane granularity).
// R17 (coalesced stage -> LDS -> warm -> emit -> store, 128 threads)
// measured 41 us with IDEAL traffic (FETCH 39.7 MB / WRITE 60 MB) but
// Occupancy 22% and VALUBusy 35-41%: 2-wave blocks + 4 barriers couple
// the waves, every stall idles a SIMD (~1.75 eff waves/SIMD). R18's
// warm-from-global decoupling attempt FAILED (+13.6 MB HBM: in-flight
// lines are NOT merged; second confirmation after R16 that per-lane
// 160B-stride global reads leak to HBM). So keep R17's memory paths
// exactly and shrink the sync domain instead:
//  - 64-thread blocks: __syncthreads degenerates to a waitcnt (s_barrier
//    with one wave retires immediately) -> no cross-wave coupling, the
//    4 phases become one schedulable instruction stream.
//  - LDS 66 slots x 176 B + 256 B ~ 11.9 KB -> 13 blocks/CU = 13
//    INDEPENDENT waves/CU (3.25/SIMD): latency hidden by TLP.
//  - staging stays fully coalesced: 660 lane-consecutive float4s
//    (10/lane + 20-lane tail), full 1 KB bursts per wave.
// Numerics byte-identical to R17 (absmax 0.0078125): 48-sample AR
// warm-up (rho^48), fp32 staging + in-place fp32 z writeback (slot
// lane+2), 9-term Neumann de-emph init (r = 0.97^40, residual ~4e-4),
// pre-signal masking, odd/even tap select, fmaf(-a,..) neg folding.
// Kept lessons: R8 scattered stores write-amplify 2.6x -> LDS-coalesced
// store; R13 no big live register arrays; R16/R18 no scattered global
// input reads.

namespace {
constexpr int kHS = 40;         // samples per half-frame
constexpr int kF = 3000;        // frames per batch
constexpr int kH = 2 * kF;      // 6000 half-frames per batch
constexpr int kL = kHS * kH;    // 240000
constexpr int kL4 = kL / 4;     // 60000 float4s per batch row
constexpr int kOrder = 16;
constexpr int kB = 64;
constexpr float kEmph = 0.97f;
constexpr int kThreads = 64;    // ONE wave per block
constexpr int kJunk = 9;        // 9-term correction needs 9 lead lanes
constexpr int kEmitH = kThreads - kJunk;  // 55 half-frames per block
constexpr int kInSlots = kThreads + 2;    // 66: warm needs lane-2..lane+1
constexpr int kIn4 = kInSlots * 10;       // 660 staged float4s
constexpr int kSlotW = 44;      // words per LDS slot (176 B, 16B-aligned)
constexpr int kCols = (kH + kEmitH - 1) / kEmitH;  // 110
constexpr float kLg97 = -4.3943347e-2f;  // log2(0.97)
// powers of r = 0.97^40
constexpr float kR1 = 0.2957118f;
constexpr float kR2 = 0.08744547f;
constexpr float kR3 = 0.02585867f;
constexpr float kR4 = 0.00764671f;
constexpr float kR5 = 0.00226126f;
constexpr float kR6 = 6.6867e-4f;
constexpr float kR7 = 1.9773e-4f;
constexpr float kR8 = 5.8472e-5f;

typedef float vfloat4 __attribute__((ext_vector_type(4)));
}  // namespace

// One AR sample; 3 partial accumulators keep the cross-sample critical
// path at 1 fma + 1 add (8 cyc) vs ~38 cyc of issue. Taps consumed as
// -A[k] via the fmaf neg source modifier (zero cost).
#define AR_SAMPLE(A, s, e_in, ACC)                                         \
  float ACC;                                                               \
  {                                                                        \
    float t0 = (e_in);                                                     \
    t0 = fmaf(-A[14], x[((s)-15) & 15], t0);                               \
    t0 = fmaf(-A[13], x[((s)-14) & 15], t0);                               \
    t0 = fmaf(-A[12], x[((s)-13) & 15], t0);                               \
    t0 = fmaf(-A[11], x[((s)-12) & 15], t0);                               \
    t0 = fmaf(-A[10], x[((s)-11) & 15], t0);                               \
    float t1 = -A[9] * x[((s)-10) & 15];                                   \
    t1 = fmaf(-A[8], x[((s)-9) & 15], t1);                                 \
    t1 = fmaf(-A[7], x[((s)-8) & 15], t1);                                 \
    t1 = fmaf(-A[6], x[((s)-7) & 15], t1);                                 \
    t1 = fmaf(-A[5], x[((s)-6) & 15], t1);                                 \
    float t2 = -A[4] * x[((s)-5) & 15];                                    \
    t2 = fmaf(-A[3], x[((s)-4) & 15], t2);                                 \
    t2 = fmaf(-A[2], x[((s)-3) & 15], t2);                                 \
    t2 = fmaf(-A[1], x[((s)-2) & 15], t2);                                 \
    const float t01 = t0 + t1;               /* off critical path */       \
    t2 = fmaf(-A[0], x[((s)-1) & 15], t2);   /* critical: 1 fma */         \
    ACC = t01 + t2;                          /* + 1 add */                 \
    x[(s)&15] = ACC;                                                       \
  }

__global__ __launch_bounds__(kThreads) void lpc_synth_kernel(
    const float* __restrict__ excit, const float* __restrict__ coef,
    float* __restrict__ out) {
  __shared__ float s_x[kInSlots * kSlotW];  // 11616 B: input, then z
  __shared__ float s_zend[kThreads];        //   256 B: per-lane zh
  __shared__ float s_zp[kEmitH];            //   220 B: per-output Zp

  const int tid = threadIdx.x;
  const int b = blockIdx.y;
  const int hbase = blockIdx.x * kEmitH;
  const int ht = hbase + tid - kJunk;  // half-frame this lane emits
  const int hc = min(max(ht, 0), kH - 1);
  const int hw = min(max(ht - 2, 0), kH - 1);
  // Slot map: slot s <-> half-frame hbase - 11 + s.
  // Lane's emit slot = tid + 2; warm slots = tid, tid + 1.

  const float* __restrict__ ebase = excit + (size_t)b * kL;
  const float* __restrict__ cbase = coef + (size_t)b * kF * kOrder;

  // ---- Coalesced staging: 660 lane-consecutive float4s (full 1 KB
  // bursts per wave), written into the padded [slot][44] LDS layout.
  // Edge clamps read junk that is masked / never stored downstream.
  {
    const vfloat4* __restrict__ eg = (const vfloat4*)ebase;
    const int base4 = (hbase - 11) * 10;  // float4 index of slot0 word0
#pragma unroll
    for (int p = 0; p < 10; ++p) {
      const int i = tid + p * kThreads;
      const int g4 = min(max(base4 + i, 0), kL4 - 1);
      const vfloat4 v = eg[g4];
      const int slot = i / 10;
      const int o = i - slot * 10;
      *(vfloat4*)(s_x + slot * kSlotW + o * 4) = v;
    }
    if (tid < kIn4 - 10 * kThreads) {  // tail: 20 float4s
      const int i = 10 * kThreads + tid;
      const int g4 = min(max(base4 + i, 0), kL4 - 1);
      const vfloat4 v = eg[g4];
      const int slot = i / 10;
      const int o = i - slot * 10;
      *(vfloat4*)(s_x + slot * kSlotW + o * 4) = v;
    }
  }

  // ---- Tap loads (prev frame for warm-up, cur frame for emit): 64 B
  // lane stride, cache-absorbed (R12-measured).
  const vfloat4* __restrict__ cp_ =
      (const vfloat4*)(cbase + (size_t)(hw >> 1) * kOrder);
  const vfloat4* __restrict__ cc_ =
      (const vfloat4*)(cbase + (size_t)(hc >> 1) * kOrder);
  const vfloat4 p0 = cp_[0], p1 = cp_[1], p2 = cp_[2], p3 = cp_[3];
  const vfloat4 q0 = cc_[0], q1 = cc_[1], q2 = cc_[2], q3 = cc_[3];

  __syncthreads();  // 1-wave block: degenerates to a waitcnt, ~free

  float pa_[15] = {p0.y, p0.z, p0.w, p1.x, p1.y, p1.z, p1.w, p2.x,
                   p2.y, p2.z, p2.w, p3.x, p3.y, p3.z, p3.w};
  const float ca_[15] = {q0.y, q0.z, q0.w, q1.x, q1.y, q1.z, q1.w, q2.x,
                         q2.y, q2.z, q2.w, q3.x, q3.y, q3.z, q3.w};

  // Ring buffer of last 16 y-samples; local sample counter s = 0..87
  // (warm 0..47, emit 48..87). Compile-time indexed -> VGPRs.
  float x[16];
#pragma unroll
  for (int i = 0; i < 16; ++i) x[i] = 0.f;

  // ---- Warm-up 48 samples from LDS (slots tid, tid+1).
  {
    const float* __restrict__ s2 = s_x + tid * kSlotW;        // ht-2
    const float* __restrict__ s1 = s_x + (tid + 1) * kSlotW;  // ht-1
    const float m2 = (ht >= 2) ? 1.f : 0.f;  // pre-signal inputs -> 0
    const float m1 = (ht >= 1) ? 1.f : 0.f;
    // Samples 0..7: tail (words 32..39) of half-frame ht-2, prev taps.
#pragma unroll
    for (int j = 8; j < 10; ++j) {
      const vfloat4 v = *(const vfloat4*)(s2 + 4 * j);
      const float f_[4] = {m2 * v.x, m2 * v.y, m2 * v.z, m2 * v.w};
#pragma unroll
      for (int q = 0; q < 4; ++q) {
        AR_SAMPLE(pa_, 4 * (j - 8) + q, f_[q], acc)
        (void)acc;
      }
    }
    // Half-frame ht-1 belongs to the emit frame when ht is odd: one-time
    // tap select (masked lanes don't care).
    if (ht & 1) {
#pragma unroll
      for (int k = 0; k < 15; ++k) pa_[k] = ca_[k];
    }
    // Samples 8..47: half-frame ht-1 in full.
#pragma unroll
    for (int j = 0; j < 10; ++j) {
      const vfloat4 v = *(const vfloat4*)(s1 + 4 * j);
      const float f_[4] = {m1 * v.x, m1 * v.y, m1 * v.z, m1 * v.w};
#pragma unroll
      for (int q = 0; q < 4; ++q) {
        AR_SAMPLE(pa_, 8 + 4 * j + q, f_[q], acc)
        (void)acc;
      }
    }
  }
  __syncthreads();  // warm reads (slots tid..tid+1) before in-place emit

  // ---- Emit 40 samples: input from own slot (tid+2), z (fp32) written
  // back IN PLACE (read v before write; no cross-lane access in emit).
  float z = 0.f;
  {
    float* __restrict__ so = s_x + (tid + 2) * kSlotW;
#pragma unroll
    for (int j = 0; j < 10; ++j) {
      const vfloat4 v = *(const vfloat4*)(so + 4 * j);
      vfloat4 zv;
#pragma unroll
      for (int q = 0; q < 4; ++q) {
        AR_SAMPLE(ca_, 48 + 4 * j + q, v[q], acc)
        z = fmaf(kEmph, z, acc);  // de-emph over this half-frame only
        if (q == 0) zv.x = z;
        if (q == 1) zv.y = z;
        if (q == 2) zv.z = z;
        if (q == 3) zv.w = z;
      }
      *(vfloat4*)(so + 4 * j) = zv;
    }
  }
  // zh = 0 outside the signal so correction terms vanish automatically.
  s_zend[tid] = (ht < 0 || ht >= kH) ? 0.f : z;
  __syncthreads();

  // ---- Per-output de-emph init (9-term Neumann, r = 0.97^40):
  // output k (block-local): Zp = sum_{i=1..9} r^(i-1) * zh[hbase+k-i],
  // i.e. s_zend[k+8] .. s_zend[k].
  if (tid < kEmitH) {
    float Zp = s_zend[tid + 8];
    Zp = fmaf(kR1, s_zend[tid + 7], Zp);
    Zp = fmaf(kR2, s_zend[tid + 6], Zp);
    Zp = fmaf(kR3, s_zend[tid + 5], Zp);
    Zp = fmaf(kR4, s_zend[tid + 4], Zp);
    Zp = fmaf(kR5, s_zend[tid + 3], Zp);
    Zp = fmaf(kR6, s_zend[tid + 2], Zp);
    Zp = fmaf(kR7, s_zend[tid + 1], Zp);
    Zp = fmaf(kR8, s_zend[tid + 0], Zp);
    s_zp[tid] = Zp;
  }
  __syncthreads();

  // ---- Coalesced store + correction: z_exact(s) = z_loc(s)+0.97^(s+1)*Zp.
  // Output k lives in slot k+11 (lane k+9's emit slot). Lane-consecutive
  // float4s: full 1 KB bursts per wave (R8/R9 lesson).
  {
    const int nv4 = min(kEmitH, kH - hbase) * 10;
    vfloat4* __restrict__ ob =
        (vfloat4*)(out + (size_t)b * kL + (size_t)hbase * kHS);
#pragma unroll 1
    for (int i = tid; i < nv4; i += kThreads) {
      const int k = i / 10;  // half-frame within block
      const int j = i - 10 * k;
      const vfloat4 h =
          *(const vfloat4*)(s_x + (k + 11) * kSlotW + 4 * j);
      const float Zp = s_zp[k];
      const float ee = __builtin_exp2f(kLg97 * (float)(4 * j + 1));
      vfloat4 v;
      v.x = fmaf(ee, Zp, h.x);
      v.y = fmaf(ee * 0.97f, Zp, h.y);
      v.z = fmaf(ee * 0.9409f, Zp, h.z);
      v.w = fmaf(ee * 0.912673f, Zp, h.w);
      ob[i] = v;
    }
  }
}
#undef AR_SAMPLE

extern "C" void kernel_launch(void* const* d_in, const int* in_sizes, int n_in,
                              void* d_out, int out_size, void* d_ws,
                              size_t ws_size, hipStream_t stream) {
  const float* excit = (const float*)d_in[0];  // (B, L, 1) fp32
  const float* coef = (const float*)d_in[1];   // (B, F, 16) fp32
  float* out = (float*)d_out;                  // (B, L, 1) fp32

  dim3 grid(kCols, kB);  // 110 x 64 single-wave blocks
  lpc_synth_kernel<<<grid, kThreads, 0, stream>>>(excit, coef, out);
}